// Round 1
// baseline (4852.620 us; speedup 1.0000x reference)
//
#include <hip/hip_runtime.h>
#include <math.h>

#define N_ 64
#define C_ 64
#define T_ 512
#define V_ 25
#define S_ 3
#define I_ 16
#define TV_ (T_*V_)          // 12800
#define NCTV_ ((size_t)N_*C_*T_*V_)  // 52428800

// ---- workspace layout (float offsets) ----
#define WS_Y      0
#define WS_MT     52428800                  // N*C*T = 2097152
#define WS_ARAW   (WS_MT + 2097152)         // 120000
#define WS_AEFF   (WS_ARAW + 120000)        // 120000
#define WS_MS     (WS_AEFF + 120000)        // 102400
#define WS_FV     (WS_MS + 102400)          // 1600
#define WS_FT     (WS_FV + 1600)            // 32768
#define WS_FC     (WS_FT + 32768)           // 4096
#define WS_BNS    (WS_FC + 4096)            // 64
#define WS_BNQ    (WS_BNS + 64)             // 64
#define WS_TBNS   (WS_BNQ + 64)             // 64
#define WS_TBNQ   (WS_TBNS + 64)            // 64
#define WS_WT     (WS_TBNQ + 64)            // 36864  tcn_w transposed [c][k][o]

// ---------------- k_prep: transpose tcn_w -> wT[(c*9+k)*64+o] ----------------
__global__ void k_prep(const float* __restrict__ tcnw, float* __restrict__ wT) {
  int e = blockIdx.x*256 + threadIdx.x;
  if (e < 64*64*9) {
    int o = e / (64*9); int r = e % (64*9); int c = r/9; int k = r%9;
    wT[(c*9+k)*64 + o] = tcnw[e];
  }
}

// ---------------- k_gram: Araw[n,s,v,w] += sum_{i,t} fa*fb ----------------
// grid (16 tchunks of 32, S, N), 128 threads
__global__ __launch_bounds__(128) void k_gram(
    const float* __restrict__ x, const float* __restrict__ Wa, const float* __restrict__ ba,
    const float* __restrict__ Wb, const float* __restrict__ bb, float* __restrict__ Araw) {
  const int tc = blockIdx.x, s = blockIdx.y, n = blockIdx.z;
  const int tid = threadIdx.x;
  const int i = tid & 15, f = (tid>>4)&1, tg = tid>>5;   // tg 0..3
  __shared__ __align__(16) float xs[4*64*28];            // [(tt*64+c)*28+v]
  __shared__ float fT[4*26*33];                          // [(tt*25+v)*33 + (i+16f)] (padded)
  // W row in registers
  float wreg[64];
  const float* Wsrc = f ? Wb : Wa;
  const float bias = (f ? bb : ba)[s*16 + i];
  #pragma unroll
  for (int c = 0; c < 64; ++c) wreg[c] = Wsrc[(s*16+i)*64 + c];
  // gram register tile: 2v x 4w ; tiles cover 25x25
  float g00=0,g01=0,g02=0,g03=0,g10=0,g11=0,g12=0,g13=0;
  const int vq = tid/7, wq = tid%7;
  const int v0 = vq*2, w0 = wq*4;
  const bool gactive = (tid < 91);

  const float* xbase = x + (size_t)n*C_*T_*V_;
  for (int it = 0; it < 8; ++it) {
    const int t0 = tc*32 + it*4;
    for (int e = tid; e < 4*64*25; e += 128) {
      int tt = e / 1600, r = e % 1600, c = r/25, v = r%25;
      xs[(tt*64+c)*28 + v] = xbase[((size_t)c*T_ + (t0+tt))*V_ + v];
    }
    __syncthreads();
    // fa/fb for (i,f) at t = t0+tg
    float4 acc4[7];
    #pragma unroll
    for (int q = 0; q < 7; ++q) acc4[q] = make_float4(bias,bias,bias,bias);
    #pragma unroll
    for (int c = 0; c < 64; ++c) {
      const float wv = wreg[c];
      const float4* row = (const float4*)&xs[(tg*64+c)*28];
      #pragma unroll
      for (int q = 0; q < 7; ++q) {
        float4 xv = row[q];
        acc4[q].x += wv*xv.x; acc4[q].y += wv*xv.y;
        acc4[q].z += wv*xv.z; acc4[q].w += wv*xv.w;
      }
    }
    const float* accf = (const float*)acc4;
    #pragma unroll
    for (int v = 0; v < 25; ++v) fT[(tg*25+v)*33 + i + 16*f] = accf[v];
    __syncthreads();
    if (gactive) {
      for (int tt = 0; tt < 4; ++tt) {
        #pragma unroll
        for (int ii = 0; ii < 16; ++ii) {
          float a0 = fT[(tt*25+v0)*33 + ii];
          float a1 = (v0+1 < 25) ? fT[(tt*25+v0+1)*33 + ii] : 0.f;
          float b0 = fT[(tt*25+w0+0)*33 + 16 + ii];
          float b1 = (w0+1<25) ? fT[(tt*25+w0+1)*33 + 16 + ii] : 0.f;
          float b2 = (w0+2<25) ? fT[(tt*25+w0+2)*33 + 16 + ii] : 0.f;
          float b3 = (w0+3<25) ? fT[(tt*25+w0+3)*33 + 16 + ii] : 0.f;
          g00 += a0*b0; g01 += a0*b1; g02 += a0*b2; g03 += a0*b3;
          g10 += a1*b0; g11 += a1*b1; g12 += a1*b2; g13 += a1*b3;
        }
      }
    }
    __syncthreads();
  }
  if (gactive) {
    float* dst = Araw + ((size_t)n*3 + s)*625;
    float gg[2][4] = {{g00,g01,g02,g03},{g10,g11,g12,g13}};
    #pragma unroll
    for (int dv = 0; dv < 2; ++dv)
      #pragma unroll
      for (int j = 0; j < 4; ++j) {
        int v = v0+dv, w = w0+j;
        if (v < 25 && w < 25) atomicAdd(&dst[v*25+w], gg[dv][j]);
      }
  }
}

// ---------------- k_finishA: Aeff = PA + alpha*tanh(Araw/8192) ----------------
__global__ void k_finishA(const float* __restrict__ Araw, const float* __restrict__ PA,
                          const float* __restrict__ alpha, float* __restrict__ Aeff) {
  int e = blockIdx.x*256 + threadIdx.x;
  if (e < 64*3*625) {
    int p = e % 625; int ns = e / 625; int s = ns % 3;
    Aeff[e] = PA[s*625 + p] + alpha[0] * tanhf(Araw[e] * (1.f/8192.f));
  }
}

// ---------------- k_gcn: y[n,o,t,w] = sum_s,c,v Wd[s,o,c] x[n,c,t,v] Aeff[n,s,v,w] ----
// grid (128 tchunks of 4, N), 256 threads
__global__ __launch_bounds__(256) void k_gcn(
    const float* __restrict__ x, const float* __restrict__ Aeff,
    const float* __restrict__ Wd, float* __restrict__ y) {
  const int tcb = blockIdx.x, n = blockIdx.y;
  const int t0 = tcb*4;
  const int tid = threadIdx.x;
  const int lo = tid & 63, tt = tid >> 6;
  __shared__ float xs[4*64*25];                    // [(tt*64+c)*25+v]
  __shared__ __align__(16) float Ap[25*28];        // [v*28+w]
  __shared__ __align__(16) float xaT[4*25*64];     // [(tt*25+w)*64+c]
  const float* xbase = x + (size_t)n*C_*T_*V_;
  for (int e = tid; e < 6400; e += 256) {
    int tti = e/1600, r = e%1600, c = r/25, v = r%25;
    xs[(tti*64+c)*25+v] = xbase[((size_t)c*T_ + t0+tti)*V_ + v];
  }
  float yacc[25];
  #pragma unroll
  for (int w = 0; w < 25; ++w) yacc[w] = 0.f;
  for (int s = 0; s < 3; ++s) {
    __syncthreads();   // covers xs staging (s=0) and prior-iter readers
    for (int e = tid; e < 625; e += 256)
      Ap[(e/25)*28 + (e%25)] = Aeff[(((size_t)n*3+s)*625) + e];
    __syncthreads();
    // xa phase: thread = (c=lo, tt)
    {
      float4 xa4[7];
      #pragma unroll
      for (int q=0;q<7;++q) xa4[q]=make_float4(0.f,0.f,0.f,0.f);
      for (int v = 0; v < 25; ++v) {
        float xsv = xs[(tt*64+lo)*25+v];
        const float4* arow = (const float4*)&Ap[v*28];
        #pragma unroll
        for (int q=0;q<7;++q) {
          float4 a = arow[q];
          xa4[q].x += xsv*a.x; xa4[q].y += xsv*a.y;
          xa4[q].z += xsv*a.z; xa4[q].w += xsv*a.w;
        }
      }
      const float* xaf = (const float*)xa4;
      #pragma unroll
      for (int w = 0; w < 25; ++w) xaT[(tt*25+w)*64 + lo] = xaf[w];
    }
    __syncthreads();
    // y phase: thread = (o=lo, tt)
    {
      const float* wrow = Wd + ((size_t)s*64 + lo)*64;
      #pragma unroll 4
      for (int c4 = 0; c4 < 16; ++c4) {
        float4 wd4 = ((const float4*)wrow)[c4];
        #pragma unroll
        for (int w = 0; w < 25; ++w) {
          float4 a = *(const float4*)&xaT[(tt*25+w)*64 + c4*4];
          yacc[w] += wd4.x*a.x + wd4.y*a.y + wd4.z*a.z + wd4.w*a.w;
        }
      }
    }
  }
  float* ybase = y + (((size_t)n*64 + lo)*T_ + t0+tt)*V_;
  #pragma unroll
  for (int w = 0; w < 25; ++w) ybase[w] = yacc[w];
}

// ---------------- k_bnstat ----------------
__global__ __launch_bounds__(256) void k_bnstat(const float* __restrict__ y,
    float* __restrict__ bns, float* __restrict__ bnq) {
  const int n = blockIdx.x, c = blockIdx.y;
  const float* base = y + ((size_t)n*64 + c)*TV_;
  float s = 0.f, q = 0.f;
  for (int j = threadIdx.x; j < 3200; j += 256) {
    float4 v = ((const float4*)base)[j];
    s += v.x+v.y+v.z+v.w;
    q += v.x*v.x+v.y*v.y+v.z*v.z+v.w*v.w;
  }
  __shared__ float rs[256], rq[256];
  rs[threadIdx.x]=s; rq[threadIdx.x]=q;
  __syncthreads();
  for (int st=128; st>0; st>>=1) {
    if (threadIdx.x < st) { rs[threadIdx.x]+=rs[threadIdx.x+st]; rq[threadIdx.x]+=rq[threadIdx.x+st]; }
    __syncthreads();
  }
  if (threadIdx.x==0) { atomicAdd(&bns[c], rs[0]); atomicAdd(&bnq[c], rq[0]); }
}

// ---------------- k_bnapply: y1 = relu(BN(y)+x) in place; Ms[n,c,v] = sum_t y1 ----
__global__ __launch_bounds__(256) void k_bnapply(
    float* __restrict__ y, const float* __restrict__ x,
    const float* __restrict__ bns, const float* __restrict__ bnq,
    const float* __restrict__ g, const float* __restrict__ b,
    float* __restrict__ Ms) {
  const int n = blockIdx.x, c = blockIdx.y;
  const float cnt = 1.f/819200.f;
  float m = bns[c]*cnt;
  float var = bnq[c]*cnt - m*m;
  float sc = g[c]*rsqrtf(var+1e-5f);
  float sh = b[c] - m*sc;
  const size_t off = ((size_t)n*64+c)*TV_;
  float* yb = y + off;
  const float* xb = x + off;
  const int v = threadIdx.x & 31, ts = threadIdx.x >> 5;
  float vs = 0.f;
  if (v < 25) {
    for (int t = ts; t < 512; t += 8) {
      int j = t*25+v;
      float val = fmaxf(sc*yb[j] + sh + xb[j], 0.f);
      yb[j] = val;
      vs += val;
    }
  }
  __shared__ float red[8][32];
  red[ts][v] = vs;
  __syncthreads();
  if (threadIdx.x < 32) {
    float t = 0.f;
    #pragma unroll
    for (int k=0;k<8;++k) t += red[k][threadIdx.x];
    if (threadIdx.x < 25) Ms[((size_t)n*64+c)*25 + threadIdx.x] = t;
  }
}

// ---------------- k_spat: fv[n,v] = 1 + sigmoid(conv_V(Ms/T)) ----------------
__global__ void k_spat(const float* __restrict__ Ms, const float* __restrict__ saw,
                       const float* __restrict__ sab, float* __restrict__ fv) {
  const int n = blockIdx.x;
  const int v = threadIdx.x;
  if (v >= 25) return;
  float acc = sab[0];
  for (int c = 0; c < 64; ++c) {
    const float* mrow = Ms + ((size_t)n*64+c)*25;
    #pragma unroll
    for (int k = 0; k < 25; ++k) {
      int vv = v + k - 12;
      if (vv >= 0 && vv < 25) acc += saw[c*25+k] * mrow[vv] * (1.f/512.f);
    }
  }
  fv[n*25+v] = 1.f + 1.f/(1.f+expf(-acc));
}

// ---------------- k_tmean: Mt[n,c,t] = (1/V) sum_v y1*fv ----------------
__global__ __launch_bounds__(256) void k_tmean(const float* __restrict__ y,
    const float* __restrict__ fv, float* __restrict__ Mt) {
  const int n = blockIdx.x, c = blockIdx.y;
  __shared__ float fvs[32];
  if (threadIdx.x < 32) fvs[threadIdx.x] = (threadIdx.x<25)? fv[n*25+threadIdx.x] : 0.f;
  __syncthreads();
  const float* yb = y + ((size_t)n*64+c)*TV_;
  float* mb = Mt + ((size_t)n*64+c)*T_;
  const int v = threadIdx.x & 31;
  const int grp = threadIdx.x >> 5;   // 0..7
  float fvv = fvs[v];
  for (int t = grp; t < 512; t += 8) {
    float val = (v<25) ? yb[t*25+v]*fvv : 0.f;
    for (int off=16; off; off>>=1) val += __shfl_down(val, off, 32);
    if (v==0) mb[t] = val * (1.f/25.f);
  }
}

// ---------------- k_tconv: ft[n,t] = 1 + sigmoid(conv_T(Mt)) ----------------
__global__ void k_tconv(const float* __restrict__ Mt, const float* __restrict__ taw,
                        const float* __restrict__ tab, float* __restrict__ ft) {
  const int n = blockIdx.x;
  __shared__ float w[64*9];
  for (int e = threadIdx.x; e < 576; e += 256) w[e] = taw[e];
  __syncthreads();
  for (int t = threadIdx.x; t < 512; t += 256) {
    float acc = tab[0];
    for (int c = 0; c < 64; ++c) {
      const float* mrow = Mt + ((size_t)n*64+c)*512;
      #pragma unroll
      for (int k = 0; k < 9; ++k) {
        int tt = t + k - 4;
        if (tt >= 0 && tt < 512) acc += w[c*9+k]*mrow[tt];
      }
    }
    ft[n*512+t] = 1.f + 1.f/(1.f+expf(-acc));
  }
}

// ---------------- k_chan: SE MLP -> fc[n,c] ----------------
__global__ void k_chan(const float* __restrict__ Mt, const float* __restrict__ ft,
    const float* __restrict__ f1w, const float* __restrict__ f1b,
    const float* __restrict__ f2w, const float* __restrict__ f2b,
    float* __restrict__ fc) {
  const int n = blockIdx.x;
  const int c = threadIdx.x;   // 64 threads
  __shared__ float m3[64], h[32];
  float acc = 0.f;
  const float* mrow = Mt + ((size_t)n*64+c)*512;
  const float* fr = ft + n*512;
  for (int t = 0; t < 512; ++t) acc += mrow[t]*fr[t];
  m3[c] = acc * (1.f/512.f);
  __syncthreads();
  if (c < 32) {
    float a = f1b[c];
    for (int j = 0; j < 64; ++j) a += f1w[c*64+j]*m3[j];
    h[c] = fmaxf(a, 0.f);
  }
  __syncthreads();
  float a = f2b[c];
  for (int j = 0; j < 32; ++j) a += f2w[c*32+j]*h[j];
  fc[n*64+c] = 1.f + 1.f/(1.f+expf(-a));
}

// ---------------- k_tcn: z = conv9x1( y1*fc*ft*fv ), fused BN2 stats ----------------
// grid (64 tchunks of 8, N), 256 threads = (o 64, g 4); each thread: 2 t rows x 25 v
__global__ __launch_bounds__(256) void k_tcn(
    const float* __restrict__ y, const float* __restrict__ fv,
    const float* __restrict__ ft, const float* __restrict__ fc,
    const float* __restrict__ wT, float* __restrict__ out,
    float* __restrict__ tbns, float* __restrict__ tbnq) {
  const int tcb = blockIdx.x, n = blockIdx.y;
  const int t0 = tcb*8;
  const int tid = threadIdx.x;
  const int o = tid & 63, g = tid >> 6;
  __shared__ __align__(16) float ys[8*16*28];   // [ci][tr][28]
  __shared__ float wch[8*9*64];                  // [(ci*9+k)*64+o]
  __shared__ float fvs[32], fcs[64], fts[16];
  __shared__ float rs[4][64], rq[4][64];
  if (tid < 32) fvs[tid] = (tid < 25) ? fv[n*25+tid] : 0.f;
  if (tid < 64) fcs[tid] = fc[n*64+tid];
  if (tid < 16) {
    int tg2 = t0 - 4 + tid;
    fts[tid] = (tg2 >= 0 && tg2 < 512) ? ft[n*512+tg2] : 0.f;
  }
  float4 z0[7], z1[7];
  #pragma unroll
  for (int q2=0;q2<7;++q2){ z0[q2]=make_float4(0.f,0.f,0.f,0.f); z1[q2]=make_float4(0.f,0.f,0.f,0.f); }
  for (int cc = 0; cc < 8; ++cc) {
    const int c0 = cc*8;
    __syncthreads();
    for (int e = tid; e < 3200; e += 256) {
      int ci = e/400, r = e%400, tr = r/25, v = r%25;
      int c = c0+ci, tg2 = t0-4+tr;
      float val = 0.f;
      if (tg2 >= 0 && tg2 < 512)
        val = y[(((size_t)n*64+c)*512 + tg2)*25 + v] * (fcs[c] * fts[tr] * fvs[v]);
      ys[(ci*16+tr)*28 + v] = val;
    }
    for (int e = tid; e < 4608; e += 256) wch[e] = wT[c0*9*64 + e];
    __syncthreads();
    #pragma unroll
    for (int ci = 0; ci < 8; ++ci) {
      float w9[9];
      #pragma unroll
      for (int k = 0; k < 9; ++k) w9[k] = wch[(ci*9+k)*64 + o];
      #pragma unroll
      for (int rr = 0; rr < 10; ++rr) {
        const float4* yrow = (const float4*)&ys[(ci*16 + g*2 + rr)*28];
        #pragma unroll
        for (int q2 = 0; q2 < 7; ++q2) {
          float4 yv = yrow[q2];
          if (rr <= 8) {
            z0[q2].x += w9[rr]*yv.x; z0[q2].y += w9[rr]*yv.y;
            z0[q2].z += w9[rr]*yv.z; z0[q2].w += w9[rr]*yv.w;
          }
          if (rr >= 1) {
            z1[q2].x += w9[rr-1]*yv.x; z1[q2].y += w9[rr-1]*yv.y;
            z1[q2].z += w9[rr-1]*yv.z; z1[q2].w += w9[rr-1]*yv.w;
          }
        }
      }
    }
  }
  const float* zf0 = (const float*)z0;
  const float* zf1 = (const float*)z1;
  float s = 0.f, qq = 0.f;
  float* ob = out + (((size_t)n*64+o)*512 + t0 + g*2)*25;
  #pragma unroll
  for (int j = 0; j < 25; ++j) {
    float a = zf0[j], b2 = zf1[j];
    ob[j] = a; ob[25+j] = b2;
    s += a + b2; qq += a*a + b2*b2;
  }
  rs[g][o] = s; rq[g][o] = qq;
  __syncthreads();
  if (tid < 64) {
    float a = rs[0][tid]+rs[1][tid]+rs[2][tid]+rs[3][tid];
    float b2 = rq[0][tid]+rq[1][tid]+rq[2][tid]+rq[3][tid];
    atomicAdd(&tbns[tid], a);
    atomicAdd(&tbnq[tid], b2);
  }
}

// ---------------- k_final: out = relu(BN2(z) + x) in place ----------------
__global__ void k_final(float* __restrict__ z, const float* __restrict__ x,
    const float* __restrict__ tbns, const float* __restrict__ tbnq,
    const float* __restrict__ tg, const float* __restrict__ tb) {
  size_t e = (size_t)blockIdx.x*256 + threadIdx.x;   // vec4 index
  if (e < NCTV_/4) {
    int c = (int)((e / 3200) & 63);
    const float cnt = 1.f/819200.f;
    float m = tbns[c]*cnt;
    float var = tbnq[c]*cnt - m*m;
    float sc = tg[c]*rsqrtf(var+1e-5f);
    float sh = tb[c] - m*sc;
    float4 zv = ((float4*)z)[e];
    float4 xv = ((const float4*)x)[e];
    float4 o;
    o.x = fmaxf(sc*zv.x+sh+xv.x, 0.f);
    o.y = fmaxf(sc*zv.y+sh+xv.y, 0.f);
    o.z = fmaxf(sc*zv.z+sh+xv.z, 0.f);
    o.w = fmaxf(sc*zv.w+sh+xv.w, 0.f);
    ((float4*)z)[e] = o;
  }
}

extern "C" void kernel_launch(void* const* d_in, const int* in_sizes, int n_in,
                              void* d_out, int out_size, void* d_ws, size_t ws_size,
                              hipStream_t stream) {
  (void)in_sizes; (void)n_in; (void)out_size; (void)ws_size;
  const float* x    = (const float*)d_in[0];
  const float* PA   = (const float*)d_in[1];
  const float* alpha= (const float*)d_in[2];
  const float* Wa   = (const float*)d_in[3];
  const float* ba   = (const float*)d_in[4];
  const float* Wb   = (const float*)d_in[5];
  const float* bb   = (const float*)d_in[6];
  const float* Wd   = (const float*)d_in[7];
  // d_in[8] = bd : per-channel bias -> cancels exactly in training-mode BN1
  const float* bng  = (const float*)d_in[9];
  const float* bnb  = (const float*)d_in[10];
  const float* saw  = (const float*)d_in[11];
  const float* sab  = (const float*)d_in[12];
  const float* taw  = (const float*)d_in[13];
  const float* tab  = (const float*)d_in[14];
  const float* f1w  = (const float*)d_in[15];
  const float* f1b  = (const float*)d_in[16];
  const float* f2w  = (const float*)d_in[17];
  const float* f2b  = (const float*)d_in[18];
  const float* tcnw = (const float*)d_in[19];
  // d_in[20] = tcn_b : cancels exactly in training-mode BN2
  const float* tbg  = (const float*)d_in[21];
  const float* tbb  = (const float*)d_in[22];

  float* ws = (float*)d_ws;
  float* out = (float*)d_out;
  float* y    = ws + WS_Y;
  float* Mt   = ws + WS_MT;
  float* Araw = ws + WS_ARAW;
  float* Aeff = ws + WS_AEFF;
  float* Ms   = ws + WS_MS;
  float* fv   = ws + WS_FV;
  float* ft   = ws + WS_FT;
  float* fc   = ws + WS_FC;
  float* bns  = ws + WS_BNS;
  float* bnq  = ws + WS_BNQ;
  float* tbns = ws + WS_TBNS;
  float* tbnq = ws + WS_TBNQ;
  float* wT   = ws + WS_WT;

  hipMemsetAsync(Araw, 0, 120000*sizeof(float), stream);
  hipMemsetAsync(bns, 0, 256*sizeof(float), stream);   // bns,bnq,tbns,tbnq contiguous

  k_prep<<<144, 256, 0, stream>>>(tcnw, wT);
  k_gram<<<dim3(16,3,64), 128, 0, stream>>>(x, Wa, ba, Wb, bb, Araw);
  k_finishA<<<469, 256, 0, stream>>>(Araw, PA, alpha, Aeff);
  k_gcn<<<dim3(128,64), 256, 0, stream>>>(x, Aeff, Wd, y);
  k_bnstat<<<dim3(64,64), 256, 0, stream>>>(y, bns, bnq);
  k_bnapply<<<dim3(64,64), 256, 0, stream>>>(y, x, bns, bnq, bng, bnb, Ms);
  k_spat<<<64, 64, 0, stream>>>(Ms, saw, sab, fv);
  k_tmean<<<dim3(64,64), 256, 0, stream>>>(y, fv, Mt);
  k_tconv<<<64, 256, 0, stream>>>(Mt, taw, tab, ft);
  k_chan<<<64, 64, 0, stream>>>(Mt, ft, f1w, f1b, f2w, f2b, fc);
  k_tcn<<<dim3(64,64), 256, 0, stream>>>(y, fv, ft, fc, wT, out, tbns, tbnq);
  k_final<<<51200, 256, 0, stream>>>(out, x, tbns, tbnq, tbg, tbb);
}

// Round 2
// 2948.914 us; speedup vs baseline: 1.6456x; 1.6456x over previous
//
#include <hip/hip_runtime.h>
#include <math.h>

#define N_ 64
#define C_ 64
#define T_ 512
#define V_ 25
#define S_ 3
#define I_ 16
#define TV_ (T_*V_)          // 12800
#define NCTV_ ((size_t)N_*C_*T_*V_)  // 52428800

// ---- workspace layout (float offsets) ----
#define WS_Y      0
#define WS_MT     52428800                  // N*C*T = 2097152
#define WS_ARAW   (WS_MT + 2097152)         // 120000
#define WS_AEFF   (WS_ARAW + 120000)        // 120000
#define WS_MS     (WS_AEFF + 120000)        // 102400
#define WS_FV     (WS_MS + 102400)          // 1600
#define WS_FT     (WS_FV + 1600)            // 32768
#define WS_FC     (WS_FT + 32768)           // 4096
#define WS_BNS    (WS_FC + 4096)            // 64
#define WS_BNQ    (WS_BNS + 64)             // 64
#define WS_TBNS   (WS_BNQ + 64)             // 64
#define WS_TBNQ   (WS_TBNS + 64)            // 64
#define WS_WT     (WS_TBNQ + 64)            // 36864 floats region; holds Apack (36864 ushort)

typedef __attribute__((ext_vector_type(8))) short bf16x8;
typedef __attribute__((ext_vector_type(4))) float f32x4;

__device__ inline ushort f2bf_rne(float x) {
  unsigned u = __float_as_uint(x);
  u = (u + 0x7FFFu + ((u >> 16) & 1u)) >> 16;
  return (ushort)u;
}

// ---------------- k_prepA: pack tcn_w into A-fragment order (bf16) ----------------
// Apack[((chunk*4 + wave)*64 + lane)*8 + jj] = bf16(w[o][c][kk])
//   chunk = kk*2 + cb ; o = wave*16 + (lane&15) ; c = cb*32 + (lane>>4)*8 + jj
__global__ void k_prepA(const float* __restrict__ tcnw, ushort* __restrict__ Apack) {
  int e = blockIdx.x*256 + threadIdx.x;
  if (e < 36864) {
    int jj = e & 7, lane = (e >> 3) & 63, wvv = (e >> 9) & 3, chunk = e >> 11;
    int kk = chunk >> 1, cb = chunk & 1;
    int o = wvv*16 + (lane & 15);
    int c = cb*32 + (lane >> 4)*8 + jj;
    Apack[e] = f2bf_rne(tcnw[(o*64 + c)*9 + kk]);
  }
}

// ---------------- k_gram: Araw[n,s,v,w] += sum_{i,t} fa*fb ----------------
__global__ __launch_bounds__(128) void k_gram(
    const float* __restrict__ x, const float* __restrict__ Wa, const float* __restrict__ ba,
    const float* __restrict__ Wb, const float* __restrict__ bb, float* __restrict__ Araw) {
  const int tc = blockIdx.x, s = blockIdx.y, n = blockIdx.z;
  const int tid = threadIdx.x;
  const int i = tid & 15, f = (tid>>4)&1, tg = tid>>5;
  __shared__ __align__(16) float xs[4*64*28];
  __shared__ float fT[4*26*33];
  float wreg[64];
  const float* Wsrc = f ? Wb : Wa;
  const float bias = (f ? bb : ba)[s*16 + i];
  #pragma unroll
  for (int c = 0; c < 64; ++c) wreg[c] = Wsrc[(s*16+i)*64 + c];
  float g00=0,g01=0,g02=0,g03=0,g10=0,g11=0,g12=0,g13=0;
  const int vq = tid/7, wq = tid%7;
  const int v0 = vq*2, w0 = wq*4;
  const bool gactive = (tid < 91);

  const float* xbase = x + (size_t)n*C_*T_*V_;
  for (int it = 0; it < 8; ++it) {
    const int t0 = tc*32 + it*4;
    for (int e = tid; e < 4*64*25; e += 128) {
      int tt = e / 1600, r = e % 1600, c = r/25, v = r%25;
      xs[(tt*64+c)*28 + v] = xbase[((size_t)c*T_ + (t0+tt))*V_ + v];
    }
    __syncthreads();
    float4 acc4[7];
    #pragma unroll
    for (int q = 0; q < 7; ++q) acc4[q] = make_float4(bias,bias,bias,bias);
    #pragma unroll
    for (int c = 0; c < 64; ++c) {
      const float wv = wreg[c];
      const float4* row = (const float4*)&xs[(tg*64+c)*28];
      #pragma unroll
      for (int q = 0; q < 7; ++q) {
        float4 xv = row[q];
        acc4[q].x += wv*xv.x; acc4[q].y += wv*xv.y;
        acc4[q].z += wv*xv.z; acc4[q].w += wv*xv.w;
      }
    }
    const float* accf = (const float*)acc4;
    #pragma unroll
    for (int v = 0; v < 25; ++v) fT[(tg*25+v)*33 + i + 16*f] = accf[v];
    __syncthreads();
    if (gactive) {
      for (int tt = 0; tt < 4; ++tt) {
        #pragma unroll
        for (int ii = 0; ii < 16; ++ii) {
          float a0 = fT[(tt*25+v0)*33 + ii];
          float a1 = (v0+1 < 25) ? fT[(tt*25+v0+1)*33 + ii] : 0.f;
          float b0 = fT[(tt*25+w0+0)*33 + 16 + ii];
          float b1 = (w0+1<25) ? fT[(tt*25+w0+1)*33 + 16 + ii] : 0.f;
          float b2 = (w0+2<25) ? fT[(tt*25+w0+2)*33 + 16 + ii] : 0.f;
          float b3 = (w0+3<25) ? fT[(tt*25+w0+3)*33 + 16 + ii] : 0.f;
          g00 += a0*b0; g01 += a0*b1; g02 += a0*b2; g03 += a0*b3;
          g10 += a1*b0; g11 += a1*b1; g12 += a1*b2; g13 += a1*b3;
        }
      }
    }
    __syncthreads();
  }
  if (gactive) {
    float* dst = Araw + ((size_t)n*3 + s)*625;
    float gg[2][4] = {{g00,g01,g02,g03},{g10,g11,g12,g13}};
    #pragma unroll
    for (int dv = 0; dv < 2; ++dv)
      #pragma unroll
      for (int j = 0; j < 4; ++j) {
        int v = v0+dv, w = w0+j;
        if (v < 25 && w < 25) atomicAdd(&dst[v*25+w], gg[dv][j]);
      }
  }
}

// ---------------- k_finishA ----------------
__global__ void k_finishA(const float* __restrict__ Araw, const float* __restrict__ PA,
                          const float* __restrict__ alpha, float* __restrict__ Aeff) {
  int e = blockIdx.x*256 + threadIdx.x;
  if (e < 64*3*625) {
    int p = e % 625; int ns = e / 625; int s = ns % 3;
    Aeff[e] = PA[s*625 + p] + alpha[0] * tanhf(Araw[e] * (1.f/8192.f));
  }
}

// ---------------- k_gcn ----------------
__global__ __launch_bounds__(256) void k_gcn(
    const float* __restrict__ x, const float* __restrict__ Aeff,
    const float* __restrict__ Wd, float* __restrict__ y) {
  const int tcb = blockIdx.x, n = blockIdx.y;
  const int t0 = tcb*4;
  const int tid = threadIdx.x;
  const int lo = tid & 63, tt = tid >> 6;
  __shared__ float xs[4*64*25];
  __shared__ __align__(16) float Ap[25*28];
  __shared__ __align__(16) float xaT[4*25*64];
  const float* xbase = x + (size_t)n*C_*T_*V_;
  for (int e = tid; e < 6400; e += 256) {
    int tti = e/1600, r = e%1600, c = r/25, v = r%25;
    xs[(tti*64+c)*25+v] = xbase[((size_t)c*T_ + t0+tti)*V_ + v];
  }
  float yacc[25];
  #pragma unroll
  for (int w = 0; w < 25; ++w) yacc[w] = 0.f;
  for (int s = 0; s < 3; ++s) {
    __syncthreads();
    for (int e = tid; e < 625; e += 256)
      Ap[(e/25)*28 + (e%25)] = Aeff[(((size_t)n*3+s)*625) + e];
    __syncthreads();
    {
      float4 xa4[7];
      #pragma unroll
      for (int q=0;q<7;++q) xa4[q]=make_float4(0.f,0.f,0.f,0.f);
      for (int v = 0; v < 25; ++v) {
        float xsv = xs[(tt*64+lo)*25+v];
        const float4* arow = (const float4*)&Ap[v*28];
        #pragma unroll
        for (int q=0;q<7;++q) {
          float4 a = arow[q];
          xa4[q].x += xsv*a.x; xa4[q].y += xsv*a.y;
          xa4[q].z += xsv*a.z; xa4[q].w += xsv*a.w;
        }
      }
      const float* xaf = (const float*)xa4;
      #pragma unroll
      for (int w = 0; w < 25; ++w) xaT[(tt*25+w)*64 + lo] = xaf[w];
    }
    __syncthreads();
    {
      const float* wrow = Wd + ((size_t)s*64 + lo)*64;
      #pragma unroll 4
      for (int c4 = 0; c4 < 16; ++c4) {
        float4 wd4 = ((const float4*)wrow)[c4];
        #pragma unroll
        for (int w = 0; w < 25; ++w) {
          float4 a = *(const float4*)&xaT[(tt*25+w)*64 + c4*4];
          yacc[w] += wd4.x*a.x + wd4.y*a.y + wd4.z*a.z + wd4.w*a.w;
        }
      }
    }
  }
  float* ybase = y + (((size_t)n*64 + lo)*T_ + t0+tt)*V_;
  #pragma unroll
  for (int w = 0; w < 25; ++w) ybase[w] = yacc[w];
}

// ---------------- k_bnstat ----------------
__global__ __launch_bounds__(256) void k_bnstat(const float* __restrict__ y,
    float* __restrict__ bns, float* __restrict__ bnq) {
  const int n = blockIdx.x, c = blockIdx.y;
  const float* base = y + ((size_t)n*64 + c)*TV_;
  float s = 0.f, q = 0.f;
  for (int j = threadIdx.x; j < 3200; j += 256) {
    float4 v = ((const float4*)base)[j];
    s += v.x+v.y+v.z+v.w;
    q += v.x*v.x+v.y*v.y+v.z*v.z+v.w*v.w;
  }
  __shared__ float rs[256], rq[256];
  rs[threadIdx.x]=s; rq[threadIdx.x]=q;
  __syncthreads();
  for (int st=128; st>0; st>>=1) {
    if (threadIdx.x < st) { rs[threadIdx.x]+=rs[threadIdx.x+st]; rq[threadIdx.x]+=rq[threadIdx.x+st]; }
    __syncthreads();
  }
  if (threadIdx.x==0) { atomicAdd(&bns[c], rs[0]); atomicAdd(&bnq[c], rq[0]); }
}

// ---------------- k_bnapply ----------------
__global__ __launch_bounds__(256) void k_bnapply(
    float* __restrict__ y, const float* __restrict__ x,
    const float* __restrict__ bns, const float* __restrict__ bnq,
    const float* __restrict__ g, const float* __restrict__ b,
    float* __restrict__ Ms) {
  const int n = blockIdx.x, c = blockIdx.y;
  const float cnt = 1.f/819200.f;
  float m = bns[c]*cnt;
  float var = bnq[c]*cnt - m*m;
  float sc = g[c]*rsqrtf(var+1e-5f);
  float sh = b[c] - m*sc;
  const size_t off = ((size_t)n*64+c)*TV_;
  float* yb = y + off;
  const float* xb = x + off;
  const int v = threadIdx.x & 31, ts = threadIdx.x >> 5;
  float vs = 0.f;
  if (v < 25) {
    for (int t = ts; t < 512; t += 8) {
      int j = t*25+v;
      float val = fmaxf(sc*yb[j] + sh + xb[j], 0.f);
      yb[j] = val;
      vs += val;
    }
  }
  __shared__ float red[8][32];
  red[ts][v] = vs;
  __syncthreads();
  if (threadIdx.x < 32) {
    float t = 0.f;
    #pragma unroll
    for (int k=0;k<8;++k) t += red[k][threadIdx.x];
    if (threadIdx.x < 25) Ms[((size_t)n*64+c)*25 + threadIdx.x] = t;
  }
}

// ---------------- k_spat ----------------
__global__ void k_spat(const float* __restrict__ Ms, const float* __restrict__ saw,
                       const float* __restrict__ sab, float* __restrict__ fv) {
  const int n = blockIdx.x;
  const int v = threadIdx.x;
  if (v >= 25) return;
  float acc = sab[0];
  for (int c = 0; c < 64; ++c) {
    const float* mrow = Ms + ((size_t)n*64+c)*25;
    #pragma unroll
    for (int k = 0; k < 25; ++k) {
      int vv = v + k - 12;
      if (vv >= 0 && vv < 25) acc += saw[c*25+k] * mrow[vv] * (1.f/512.f);
    }
  }
  fv[n*25+v] = 1.f + 1.f/(1.f+expf(-acc));
}

// ---------------- k_tmean ----------------
__global__ __launch_bounds__(256) void k_tmean(const float* __restrict__ y,
    const float* __restrict__ fv, float* __restrict__ Mt) {
  const int n = blockIdx.x, c = blockIdx.y;
  __shared__ float fvs[32];
  if (threadIdx.x < 32) fvs[threadIdx.x] = (threadIdx.x<25)? fv[n*25+threadIdx.x] : 0.f;
  __syncthreads();
  const float* yb = y + ((size_t)n*64+c)*TV_;
  float* mb = Mt + ((size_t)n*64+c)*T_;
  const int v = threadIdx.x & 31;
  const int grp = threadIdx.x >> 5;
  float fvv = fvs[v];
  for (int t = grp; t < 512; t += 8) {
    float val = (v<25) ? yb[t*25+v]*fvv : 0.f;
    for (int off=16; off; off>>=1) val += __shfl_down(val, off, 32);
    if (v==0) mb[t] = val * (1.f/25.f);
  }
}

// ---------------- k_tconv ----------------
__global__ void k_tconv(const float* __restrict__ Mt, const float* __restrict__ taw,
                        const float* __restrict__ tab, float* __restrict__ ft) {
  const int n = blockIdx.x;
  __shared__ float w[64*9];
  for (int e = threadIdx.x; e < 576; e += 256) w[e] = taw[e];
  __syncthreads();
  for (int t = threadIdx.x; t < 512; t += 256) {
    float acc = tab[0];
    for (int c = 0; c < 64; ++c) {
      const float* mrow = Mt + ((size_t)n*64+c)*512;
      #pragma unroll
      for (int k = 0; k < 9; ++k) {
        int tt = t + k - 4;
        if (tt >= 0 && tt < 512) acc += w[c*9+k]*mrow[tt];
      }
    }
    ft[n*512+t] = 1.f + 1.f/(1.f+expf(-acc));
  }
}

// ---------------- k_chan ----------------
__global__ void k_chan(const float* __restrict__ Mt, const float* __restrict__ ft,
    const float* __restrict__ f1w, const float* __restrict__ f1b,
    const float* __restrict__ f2w, const float* __restrict__ f2b,
    float* __restrict__ fc) {
  const int n = blockIdx.x;
  const int c = threadIdx.x;
  __shared__ float m3[64], h[32];
  float acc = 0.f;
  const float* mrow = Mt + ((size_t)n*64+c)*512;
  const float* fr = ft + n*512;
  for (int t = 0; t < 512; ++t) acc += mrow[t]*fr[t];
  m3[c] = acc * (1.f/512.f);
  __syncthreads();
  if (c < 32) {
    float a = f1b[c];
    for (int j = 0; j < 64; ++j) a += f1w[c*64+j]*m3[j];
    h[c] = fmaxf(a, 0.f);
  }
  __syncthreads();
  float a = f2b[c];
  for (int j = 0; j < 32; ++j) a += f2w[c*32+j]*h[j];
  fc[n*64+c] = 1.f + 1.f/(1.f+expf(-a));
}

// ---------------- k_tcnm: MFMA bf16 TCN ----------------
// z[n][o][j] = sum_{c,kk} w[o][c][kk] * ytil[n][c][j+(kk-4)*25],  j = t*25+v
// ytil = y1 * fc[c] * ft[t] * fv[v], zero-padded in t.
// grid (50 j-tiles of 256, N), 256 threads = 4 waves; wave w -> o-tile w*16.
#define BROW 456
#define BSTR 72        // bf16 units; conflict-free for b128 writes and frag reads
__global__ __launch_bounds__(256) void k_tcnm(
    const float* __restrict__ y, const float* __restrict__ fv,
    const float* __restrict__ ft, const float* __restrict__ fc,
    const ushort* __restrict__ Apack, float* __restrict__ out,
    float* __restrict__ tbns, float* __restrict__ tbnq) {
  const int jt = blockIdx.x, n = blockIdx.y;
  const int j0 = jt*256;
  const int tid = threadIdx.x;
  const int lane = tid & 63, wv = tid >> 6;
  __shared__ __align__(16) ushort Bs[BROW*BSTR];   // 65664 B
  __shared__ float fts[512], fvs[32], fcs[64];
  for (int e = tid; e < 512; e += 256) fts[e] = ft[n*512+e];
  if (tid < 32) fvs[tid] = (tid < 25) ? fv[n*25+tid] : 0.f;
  if (tid >= 64 && tid < 128) fcs[tid-64] = fc[n*64 + tid-64];
  __syncthreads();
  // ---- stage Bs[j][c] = bf16(ytil), j in [j0-100, j0+356) ----
  const float* yb = y + (size_t)n*64*TV_;
  for (int item = wv; item < 64; item += 4) {     // item = jc*8 + ce
    int jc = item >> 3, ce = item & 7;
    int j = jc*64 + lane;
    if (j < BROW) {
      int jg = j0 - 100 + j;
      unsigned p0=0,p1=0,p2=0,p3=0;
      if (jg >= 0 && jg < TV_) {
        int t = jg / 25, v = jg - t*25;
        float f = fts[t]*fvs[v];
        ushort pk[8];
        #pragma unroll
        for (int r = 0; r < 8; ++r) {
          int c = ce*8 + r;
          pk[r] = f2bf_rne(yb[(size_t)c*TV_ + jg] * f * fcs[c]);
        }
        p0 = (unsigned)pk[0] | ((unsigned)pk[1]<<16);
        p1 = (unsigned)pk[2] | ((unsigned)pk[3]<<16);
        p2 = (unsigned)pk[4] | ((unsigned)pk[5]<<16);
        p3 = (unsigned)pk[6] | ((unsigned)pk[7]<<16);
      }
      uint4 w4; w4.x=p0; w4.y=p1; w4.z=p2; w4.w=p3;
      *(uint4*)&Bs[j*BSTR + ce*8] = w4;
    }
  }
  __syncthreads();
  // ---- MFMA K-loop: 18 chunks of K=32 (kk outer, c-half inner) ----
  const int l15 = lane & 15, l4 = lane >> 4;
  f32x4 acc[16];
  #pragma unroll
  for (int i = 0; i < 16; ++i) acc[i] = (f32x4){0.f,0.f,0.f,0.f};
  for (int kk = 0; kk < 9; ++kk) {
    #pragma unroll
    for (int cb = 0; cb < 2; ++cb) {
      const int chunk = kk*2 + cb;
      bf16x8 afrag = *(const bf16x8*)(Apack + (size_t)((chunk*4 + wv)*64 + lane)*8);
      const int rbase = kk*25 + l15;
      const int ccol = cb*32 + l4*8;
      #pragma unroll
      for (int jt2 = 0; jt2 < 16; ++jt2) {
        bf16x8 bfrag = *(const bf16x8*)&Bs[(rbase + jt2*16)*BSTR + ccol];
        acc[jt2] = __builtin_amdgcn_mfma_f32_16x16x32_bf16(afrag, bfrag, acc[jt2], 0, 0, 0);
      }
    }
  }
  // ---- epilogue: store z + BN2 stats ----
  float so[4] = {0,0,0,0}, qo[4] = {0,0,0,0};
  const int obase = wv*16 + l4*4;
  #pragma unroll
  for (int jt2 = 0; jt2 < 16; ++jt2) {
    const int j = j0 + jt2*16 + l15;
    #pragma unroll
    for (int r = 0; r < 4; ++r) {
      float val = acc[jt2][r];
      out[((size_t)n*64 + obase + r)*TV_ + j] = val;
      so[r] += val; qo[r] += val*val;
    }
  }
  #pragma unroll
  for (int off = 1; off < 16; off <<= 1) {
    #pragma unroll
    for (int r = 0; r < 4; ++r) {
      so[r] += __shfl_xor(so[r], off);
      qo[r] += __shfl_xor(qo[r], off);
    }
  }
  if (l15 == 0) {
    #pragma unroll
    for (int r = 0; r < 4; ++r) {
      atomicAdd(&tbns[obase + r], so[r]);
      atomicAdd(&tbnq[obase + r], qo[r]);
    }
  }
}

// ---------------- k_final ----------------
__global__ void k_final(float* __restrict__ z, const float* __restrict__ x,
    const float* __restrict__ tbns, const float* __restrict__ tbnq,
    const float* __restrict__ tg, const float* __restrict__ tb) {
  size_t e = (size_t)blockIdx.x*256 + threadIdx.x;
  if (e < NCTV_/4) {
    int c = (int)((e / 3200) & 63);
    const float cnt = 1.f/819200.f;
    float m = tbns[c]*cnt;
    float var = tbnq[c]*cnt - m*m;
    float sc = tg[c]*rsqrtf(var+1e-5f);
    float sh = tb[c] - m*sc;
    float4 zv = ((float4*)z)[e];
    float4 xv = ((const float4*)x)[e];
    float4 o;
    o.x = fmaxf(sc*zv.x+sh+xv.x, 0.f);
    o.y = fmaxf(sc*zv.y+sh+xv.y, 0.f);
    o.z = fmaxf(sc*zv.z+sh+xv.z, 0.f);
    o.w = fmaxf(sc*zv.w+sh+xv.w, 0.f);
    ((float4*)z)[e] = o;
  }
}

extern "C" void kernel_launch(void* const* d_in, const int* in_sizes, int n_in,
                              void* d_out, int out_size, void* d_ws, size_t ws_size,
                              hipStream_t stream) {
  (void)in_sizes; (void)n_in; (void)out_size; (void)ws_size;
  const float* x    = (const float*)d_in[0];
  const float* PA   = (const float*)d_in[1];
  const float* alpha= (const float*)d_in[2];
  const float* Wa   = (const float*)d_in[3];
  const float* ba   = (const float*)d_in[4];
  const float* Wb   = (const float*)d_in[5];
  const float* bb   = (const float*)d_in[6];
  const float* Wd   = (const float*)d_in[7];
  // d_in[8] = bd : cancels exactly in training-mode BN1
  const float* bng  = (const float*)d_in[9];
  const float* bnb  = (const float*)d_in[10];
  const float* saw  = (const float*)d_in[11];
  const float* sab  = (const float*)d_in[12];
  const float* taw  = (const float*)d_in[13];
  const float* tab  = (const float*)d_in[14];
  const float* f1w  = (const float*)d_in[15];
  const float* f1b  = (const float*)d_in[16];
  const float* f2w  = (const float*)d_in[17];
  const float* f2b  = (const float*)d_in[18];
  const float* tcnw = (const float*)d_in[19];
  // d_in[20] = tcn_b : cancels exactly in training-mode BN2
  const float* tbg  = (const float*)d_in[21];
  const float* tbb  = (const float*)d_in[22];

  float* ws = (float*)d_ws;
  float* out = (float*)d_out;
  float* y    = ws + WS_Y;
  float* Mt   = ws + WS_MT;
  float* Araw = ws + WS_ARAW;
  float* Aeff = ws + WS_AEFF;
  float* Ms   = ws + WS_MS;
  float* fv   = ws + WS_FV;
  float* ft   = ws + WS_FT;
  float* fc   = ws + WS_FC;
  float* bns  = ws + WS_BNS;
  float* bnq  = ws + WS_BNQ;
  float* tbns = ws + WS_TBNS;
  float* tbnq = ws + WS_TBNQ;
  ushort* Apack = (ushort*)(ws + WS_WT);

  hipMemsetAsync(Araw, 0, 120000*sizeof(float), stream);
  hipMemsetAsync(bns, 0, 256*sizeof(float), stream);   // bns,bnq,tbns,tbnq contiguous

  k_prepA<<<144, 256, 0, stream>>>(tcnw, Apack);
  k_gram<<<dim3(16,3,64), 128, 0, stream>>>(x, Wa, ba, Wb, bb, Araw);
  k_finishA<<<469, 256, 0, stream>>>(Araw, PA, alpha, Aeff);
  k_gcn<<<dim3(128,64), 256, 0, stream>>>(x, Aeff, Wd, y);
  k_bnstat<<<dim3(64,64), 256, 0, stream>>>(y, bns, bnq);
  k_bnapply<<<dim3(64,64), 256, 0, stream>>>(y, x, bns, bnq, bng, bnb, Ms);
  k_spat<<<64, 64, 0, stream>>>(Ms, saw, sab, fv);
  k_tmean<<<dim3(64,64), 256, 0, stream>>>(y, fv, Mt);
  k_tconv<<<64, 256, 0, stream>>>(Mt, taw, tab, ft);
  k_chan<<<64, 64, 0, stream>>>(Mt, ft, f1w, f1b, f2w, f2b, fc);
  k_tcnm<<<dim3(50,64), 256, 0, stream>>>(y, fv, ft, fc, Apack, out, tbns, tbnq);
  k_final<<<51200, 256, 0, stream>>>(out, x, tbns, tbnq, tbg, tbb);
}